// Round 5
// baseline (413.175 us; speedup 1.0000x reference)
//
#include <hip/hip_runtime.h>
#include <math.h>

#define NN 50000
#define EE 800000
#define ETOT (EE + NN)
#define NGR 64
#define DD 128
#define NCL 10

#define NBUK 128
#define BNODES 391            // 128*391 = 50048 >= NN
#define P1CH 3321             // ceil(ETOT/256)
#define P2CAP 8704            // LDS entry cap per bucket (mean ~6650)
#define TCAP 12288            // per-bucket tmp capacity (mean 6641, +69 sigma)

typedef __attribute__((ext_vector_type(16))) float float16_t;
typedef __attribute__((ext_vector_type(8)))  __bf16 bf16x8;

// ---------------- device helpers ----------------
__device__ __forceinline__ float siluf(float x){ return x / (1.f + __expf(-x)); }

__device__ __forceinline__ unsigned f2bf(float f){
  union { float f; unsigned u; } v; v.f = f;
  unsigned r = v.u + 0x7fffu + ((v.u >> 16) & 1u);
  return (r >> 16) & 0xffffu;
}

__device__ __forceinline__ float bflo(unsigned u){ return __uint_as_float(u << 16); }
__device__ __forceinline__ float bfhi(unsigned u){ return __uint_as_float(u & 0xffff0000u); }

// 8 KAN features of scalar x: [silu(x), B0..B6] (float version for readout)
__device__ __forceinline__ void kan_feats(float x, float* f8){
  f8[0] = siluf(x);
  float u = 2.f*x + 5.f;
  int cell = -1;
  float n0=0.f,n1=0.f,n2=0.f,n3=0.f;
  if (u >= 0.f && u < 10.f){
    cell = (int)u;
    float t = u - (float)cell;
    float t2 = t*t, t3 = t2*t;
    float omt = 1.f - t;
    const float s6 = 1.f/6.f;
    n0 = t3*s6;
    n1 = s6*(1.f + 3.f*t + 3.f*t2 - 3.f*t3);
    n2 = s6*(4.f - 6.f*t2 + 3.f*t3);
    n3 = omt*omt*omt*s6;
  }
#pragma unroll
  for (int j=0;j<7;++j){
    int k = cell - j;
    float v = (k==0)?n0:((k==1)?n1:((k==2)?n2:((k==3)?n3:0.f)));
    f8[1+j] = v;
  }
}

// Packed bf16 A-fragment of scalar x: us[0..7] = [silu, B0..B6] via 64-bit shift.
__device__ __forceinline__ int4 kan_feats_pack(float x){
  unsigned sbf = f2bf(siluf(x));
  float u = 2.f*x + 5.f;
  bool valid = (u >= 0.f) && (u < 10.f);
  float uc = valid ? u : 0.f;
  int cell = (int)uc;
  float t = uc - (float)cell;
  float t2 = t*t, t3 = t2*t, omt = 1.f - t;
  const float s6 = 1.f/6.f;
  float n0 = t3*s6;
  float n1 = s6*(1.f + 3.f*t + 3.f*t2 - 3.f*t3);
  float n2 = s6*(4.f - 6.f*t2 + 3.f*t3);
  float n3 = omt*omt*omt*s6;
  unsigned p0=f2bf(n0), p1=f2bf(n1), p2=f2bf(n2), p3=f2bf(n3);
  unsigned long long P = ((unsigned long long)(p1 | (p0<<16)) << 32)
                       |  (unsigned long long)(p3 | (p2<<16));
  int sh = cell*16 - 48;
  unsigned long long shl    = P << (sh & 63);
  unsigned long long shrhi  = P >> ((64 - sh) & 63);
  unsigned long long shllo2 = P << ((sh - 64) & 63);
  unsigned long long shrlo  = P >> ((-sh) & 63);
  unsigned long long F0, F1;
  if (sh < 0)       { F0 = shrlo; F1 = 0ull; }
  else if (sh < 64) { F0 = shl;   F1 = (sh==0)? 0ull : shrhi; }
  else              { F0 = 0ull;  F1 = shllo2; }
  if (!valid){ F0 = 0ull; F1 = 0ull; }
  unsigned w0 = ((unsigned)(F0 & 0xffffull) << 16) | sbf;
  unsigned w1 = (unsigned)((F0 >> 16) & 0xffffffffull);
  unsigned w2 = (unsigned)((F0 >> 48) & 0xffffull) | (((unsigned)(F1 & 0xffffull)) << 16);
  unsigned w3 = (unsigned)((F1 >> 16) & 0xffffffffull);
  return make_int4((int)w0,(int)w1,(int)w2,(int)w3);
}

// ---------------- CSR build v3: 2 kernels, bucket-strided tmp ----------------
// Pass 1 (multisplit): each block owns a contiguous edge slice; LDS-sorts it by
// dst-bucket (128 buckets of 391 nodes) and flushes bucket-contiguous runs into
// tmp[b*TCAP + rel], reserving space with ONE global atomic per (block,bucket).
// bcur starts at 0; after this kernel bcur[b] == bucket b's total count.
// tmp entry: (bucket<<25) | (dstLocal<<16) | src   (src < 65536 fits 16 bits)
__global__ __launch_bounds__(256) void binpass_kernel(const int* __restrict__ ei,
                                                      int* __restrict__ bcur,
                                                      unsigned* __restrict__ tmp){
  __shared__ int cnt[NBUK], lexcl[NBUK], gbase[NBUK], lcur[NBUK];
  __shared__ int sc[NBUK];
  __shared__ unsigned entries[P1CH + 7];
  const int t = threadIdx.x;
  const int e0 = blockIdx.x * P1CH;
  int e1 = e0 + P1CH; if (e1 > ETOT) e1 = ETOT;
  const int total = e1 - e0;

  if (t < NBUK){ cnt[t] = 0; lcur[t] = 0; }
  __syncthreads();

  // pass A: bucket histogram
  for (int e = e0 + t; e < e1; e += 256){
    int dst = (e < EE) ? ei[EE + e] : (e - EE);
    int b = dst / BNODES;
    atomicAdd(&cnt[b], 1);
  }
  __syncthreads();

  // exclusive scan of cnt over 128 buckets
  if (t < NBUK) sc[t] = cnt[t];
  __syncthreads();
  for (int o=1;o<NBUK;o<<=1){
    int v = 0;
    if (t < NBUK && t >= o) v = sc[t - o];
    __syncthreads();
    if (t < NBUK) sc[t] += v;
    __syncthreads();
  }
  if (t < NBUK) lexcl[t] = sc[t] - cnt[t];
  __syncthreads();

  // reserve per-bucket chunks (bcur starts at 0)
  if (t < NBUK && cnt[t] > 0) gbase[t] = atomicAdd(&bcur[t], cnt[t]);
  __syncthreads();

  // pass B: re-read and place into LDS sorted-by-bucket
  for (int e = e0 + t; e < e1; e += 256){
    int src, dst;
    if (e < EE){ src = ei[e]; dst = ei[EE + e]; } else { src = e - EE; dst = src; }
    int b = dst / BNODES;
    int dl = dst - b*BNODES;
    int r = lexcl[b] + atomicAdd(&lcur[b], 1);
    entries[r] = ((unsigned)b << 25) | ((unsigned)dl << 16) | (unsigned)src;
  }
  __syncthreads();

  // flush: consecutive slots -> consecutive tmp positions within a bucket
  for (int s = t; s < total; s += 256){
    unsigned en = entries[s];
    int b = en >> 25;
    int rel = gbase[b] + (s - lexcl[b]);
    if (rel < TCAP) tmp[(size_t)b*TCAP + rel] = en;
  }
}

// Pass 2: one block per bucket. Derives bucket base from the 128 bucket counts
// (LDS reduce), builds per-dst histogram+scan, writes offs/deg for its nodes,
// then groups the bucket by dst in LDS and writes the csr window coalesced.
__global__ __launch_bounds__(256) void scatter_kernel(const unsigned* __restrict__ tmp,
                                                      const int* __restrict__ bcur,
                                                      int* __restrict__ offs,
                                                      int* __restrict__ deg,
                                                      int* __restrict__ csr){
  __shared__ unsigned sbuf[P2CAP];
  __shared__ int dcnt[BNODES+1], dscan[BNODES+1], dcur[BNODES+1];
  __shared__ int sA[512], sB[512];
  const int t = threadIdx.x;
  const int b = blockIdx.x;
  const int lo = b * BNODES;

  // bucket base = sum of counts of buckets < b (tree reduce over 128)
  if (t < NBUK) sA[t] = (t < b) ? bcur[t] : 0;
  __syncthreads();
  for (int o=64;o>=1;o>>=1){ if (t < o && t+o < NBUK) sA[t] += sA[t+o]; __syncthreads(); }
  const int base = sA[0];
  const int cntb_raw = bcur[b];
  const int cntb = (cntb_raw < TCAP) ? cntb_raw : TCAP;
  const unsigned* tw = tmp + (size_t)b*TCAP;

  for (int i = t; i < BNODES+1; i += 256){ dcnt[i] = 0; dcur[i] = 0; }
  __syncthreads();
  for (int i = t; i < cntb; i += 256){
    int dl = (tw[i] >> 16) & 0x1FF;
    atomicAdd(&dcnt[dl], 1);
  }
  __syncthreads();

  // exclusive scan over 392 counters (padded to 512, double-buffered H-S)
  sA[t]       = (t       < BNODES+1) ? dcnt[t]       : 0;
  sA[t + 256] = (t + 256 < BNODES+1) ? dcnt[t + 256] : 0;
  __syncthreads();
  int* sp = sA; int* dp = sB;
  for (int o=1;o<512;o<<=1){
    dp[t]       = sp[t]       + ((t       >= o) ? sp[t - o]       : 0);
    dp[t + 256] = sp[t + 256] + ((t + 256 >= o) ? sp[t + 256 - o] : 0);
    __syncthreads();
    int* tpp = sp; sp = dp; dp = tpp;
  }
  if (t       < BNODES+1) dscan[t]       = sp[t]       - dcnt[t];
  if (t + 256 < BNODES+1) dscan[t + 256] = sp[t + 256] - dcnt[t + 256];
  __syncthreads();

  // per-node offsets + degrees (replaces the global scan chain)
  for (int dl = t; dl < BNODES; dl += 256){
    int node = lo + dl;
    if (node < NN){ offs[node] = base + dscan[dl]; deg[node] = dcnt[dl]; }
  }

  if (cntb <= P2CAP){
    // LDS scatter by dstLocal, then fully-coalesced csr write
    for (int i = t; i < cntb; i += 256){
      unsigned en = tw[i];
      int dl = (en >> 16) & 0x1FF;
      int r = dscan[dl] + atomicAdd(&dcur[dl], 1);
      sbuf[r] = en & 0xFFFFu;
    }
    __syncthreads();
    for (int i = t; i < cntb; i += 256) csr[base + i] = (int)sbuf[i];
  } else {
    // fallback (statistically impossible): direct scattered writes
    for (int i = t; i < cntb; i += 256){
      unsigned en = tw[i];
      int dl = (en >> 16) & 0x1FF;
      int r = dscan[dl] + atomicAdd(&dcur[dl], 1);
      csr[base + r] = (int)(en & 0xFFFFu);
    }
  }
}

// ---------------- fold weights into bf16, MFMA-fragment order ----------------
__global__ void build_wfrag(const float* __restrict__ bw, const float* __restrict__ sw,
                            const float* __restrict__ sc, unsigned short* __restrict__ wfrag){
  int idx = blockIdx.x*256 + threadIdx.x;
  if (idx >= 3*128*1024) return;
  int k = idx & 1023;
  int o = (idx >> 10) & 127;
  int l = idx >> 17;
  int i = k >> 3, f = k & 7;
  int oi = (l*DD + o)*DD + i;
  float w = (f == 0) ? bw[oi] : sw[oi*7 + (f-1)] * sc[oi];
  int s = k >> 6;
  int sl = (k >> 4) & 3, half = (k >> 3) & 1, j = k & 7;
  int ntile = o >> 5, n = o & 31;
  int dst = l*131072 + s*8192 + (((ntile*4 + sl)*64) + half*32 + n)*8 + j;
  wfrag[dst] = (unsigned short)f2bf(w);
}

// ---------------- fused KAN feats + GEMM + pack + attention logits ----------------
// 32-row tile / 1563 blocks: LDS 25 KB (xs 32x132 f32 + Afrag 2x2048 bf16).
// launch_bounds(256,4): VGPR cap 128 so the Bc/Bn double-buffer + acc stay in
// registers. LDS caps residency at 6 blocks/CU.
__global__ __launch_bounds__(256, 4) void kan_gemm(const float* __restrict__ xin,
                                                const unsigned short* __restrict__ wfrag,
                                                const float* __restrict__ attS,
                                                const float* __restrict__ attD,
                                                unsigned int* __restrict__ hpack,
                                                float* __restrict__ asrc,
                                                float* __restrict__ adst, int layer)
{
  __shared__ __align__(16) float xs[32*132];               // 16896 B (reused as hs)
  __shared__ __align__(16) unsigned short Afrag[2][2048];  // 8192 B
  const int t    = threadIdx.x;
  const int lane = t & 63;
  const int w    = t >> 6;          // wave -> output col tile w*32
  const int half = lane >> 5;
  const int mn   = lane & 31;
  const int row0 = blockIdx.x * 32;
  const int r_my = t & 31;          // row this thread packs
  const int j_my = t >> 5;          // col-in-step this thread packs (0..7)
  const unsigned short* wl = wfrag + layer*131072;

  // stage x rows [row0, row0+32) x 128 cols, float4-coalesced
#pragma unroll
  for (int q=0;q<4;++q){
    int p = q*256 + t;
    int r = p >> 5, c4 = p & 31;
    int grow = row0 + r;
    float4 v = make_float4(0.f,0.f,0.f,0.f);
    if (grow < NN) v = *(const float4*)(xin + (size_t)grow*DD + c4*4);
    *(float4*)(&xs[r*132 + c4*4]) = v;
  }
  __syncthreads();

  float16_t acc;
#pragma unroll
  for (int i=0;i<16;++i) acc[i]=0.f;

  int4 Bc[4], Bn[4];
#pragma unroll
  for (int sl=0;sl<4;++sl)
    Bc[sl] = *(const int4*)(wl + ((w*4+sl)*64 + lane)*8);

  // Afrag slot for (col j, row r) = ((j*32 + r)*8) ushorts
  const int fo = (j_my*32 + r_my)*8;
  {
    int4 P = kan_feats_pack(xs[r_my*132 + j_my]);
    *(int4*)(&Afrag[0][fo]) = P;
  }
  __syncthreads();

  for (int s=0; s<16; ++s){
    if (s < 15){
      const unsigned short* wsrc = wl + (s+1)*8192;
#pragma unroll
      for (int sl=0;sl<4;++sl)
        Bn[sl] = *(const int4*)(wsrc + ((w*4+sl)*64 + lane)*8);
      int4 P = kan_feats_pack(xs[r_my*132 + (s+1)*8 + j_my]);
      *(int4*)(&Afrag[(s+1)&1][fo]) = P;
    }
    const unsigned short* A = Afrag[s&1];
#pragma unroll
    for (int sl=0; sl<4; ++sl){
      int4 ai = *(const int4*)(A + ((sl*2 + half)*32 + mn)*8);
      bf16x8 b = __builtin_bit_cast(bf16x8, Bc[sl]);
      acc = __builtin_amdgcn_mfma_f32_32x32x16_bf16(__builtin_bit_cast(bf16x8, ai), b, acc, 0, 0, 0);
    }
#pragma unroll
    for (int sl=0;sl<4;++sl) Bc[sl] = Bn[sl];
    __syncthreads();
  }

  // epilogue: bf16-pack into LDS (reuse xs), then coalesced hpack write + att logits
  unsigned short* hs = (unsigned short*)xs;
#pragma unroll
  for (int reg=0; reg<16; ++reg){
    int row = (reg&3) + 8*(reg>>2) + 4*half;
    int col = w*32 + mn;
    hs[row*136 + col] = (unsigned short)f2bf(acc[reg]);
  }
  __syncthreads();
#pragma unroll
  for (int q=0;q<2;++q){
    int p = q*256 + t;
    int row = p >> 4, u4 = p & 15;
    uint4 v = *(const uint4*)((const unsigned int*)(hs + row*136) + u4*4);
    int grow = row0 + row;
    if (grow < NN) *(uint4*)(hpack + (size_t)grow*64 + u4*4) = v;
  }
  if (t < 128){
    int r = t >> 2, h = t & 3;
    const unsigned* hrow = (const unsigned*)(hs + r*136) + h*16;
    const float* ws = attS + (layer*4 + h)*32;
    const float* wd = attD + (layer*4 + h)*32;
    float ss = 0.f, sd = 0.f;
#pragma unroll
    for (int j=0;j<16;++j){
      unsigned u = hrow[j];
      float flo = __uint_as_float(u << 16);
      float fhi = __uint_as_float(u & 0xffff0000u);
      ss += flo*ws[2*j] + fhi*ws[2*j+1];
      sd += flo*wd[2*j] + fhi*wd[2*j+1];
    }
    int grow = row0 + r;
    if (grow < NN){ asrc[grow*4 + h] = ss; adst[grow*4 + h] = sd; }
  }
}

// ---------------- GAT aggregation v7: issue-early gather ------------------------
// All (up to 16) uint4 gathers of the d<=64 path are issued BEFORE any FMA
// consumes them: MLP per wave 4 -> 16 so the ~500cy L2/L3 gather latency is
// covered (occupancy is stuck at ~64% regardless -- measured VGPR=24 round 4,
// so extra registers here are free until ~96).
__global__ __launch_bounds__(256) void attn_kernel(
    const unsigned int* __restrict__ hpack, const float* __restrict__ asrc, const float* __restrict__ adst,
    const int* __restrict__ offs, const int* __restrict__ deg, const int* __restrict__ csr,
    const float* __restrict__ bias, float* __restrict__ hout, int layer)
{
  const int wave = threadIdx.x >> 6;
  const int lane = threadIdx.x & 63;
  const int n = blockIdx.x*4 + wave;
  if (n >= NN) return;
  const int st = offs[n];
  const int d  = deg[n];
  const int eL = lane >> 2, h = lane & 3;
  const float adh = adst[n*4 + h];

  // ---- phase 1: logits, running max ----
  int   srcv[4];
  float ev[4];
  float mL = -3.4e38f;
#pragma unroll
  for (int c=0;c<4;++c){
    srcv[c] = 0; ev[c] = -3.4e38f;
    if (c*16 < d){
      int e = c*16 + eL;
      if (e < d){
        int s2 = csr[st + e];
        srcv[c] = s2;
        float e0 = asrc[s2*4 + h] + adh;
        ev[c] = (e0 > 0.f) ? e0 : 0.2f*e0;
        mL = fmaxf(mL, ev[c]);
      }
    }
  }
  for (int c=64; c<d; c+=16){
    int e = c + eL;
    if (e < d){
      int s2 = csr[st + e];
      float e0 = asrc[s2*4 + h] + adh;
      float evv = (e0 > 0.f) ? e0 : 0.2f*e0;
      mL = fmaxf(mL, evv);
    }
  }
#pragma unroll
  for (int o=4;o<64;o<<=1) mL = fmaxf(mL, __shfl_xor(mL, o));

  // ---- phase 2: softmax denominator ----
  float av4[4];
  float sL = 0.f;
#pragma unroll
  for (int c=0;c<4;++c){ av4[c] = __expf(ev[c] - mL); sL += av4[c]; }
  for (int c=64; c<d; c+=16){
    int e = c + eL;
    if (e < d){
      int s2 = csr[st + e];
      float e0 = asrc[s2*4 + h] + adh;
      float evv = (e0 > 0.f) ? e0 : 0.2f*e0;
      sL += __expf(evv - mL);
    }
  }
#pragma unroll
  for (int o=4;o<64;o<<=1) sL += __shfl_xor(sL, o);
  const float inv = 1.f/(sL + 1e-16f);

  // ---- phase 3: weighted gather, uint4 layout, issue-early ----
  // lane covers cols [8*cl, 8*cl+8) of row (g*4 + cq) in each 4-edge group
  const int cq   = lane >> 4;      // row-in-group 0..3
  const int cl   = lane & 15;      // col-quad 0..15
  const int hsel = cl >> 2;        // head owning my cols
  float acc8[8];
#pragma unroll
  for (int k=0;k<8;++k) acc8[k] = 0.f;

  // A) issue all gathers (static-indexed register file; wave-uniform guards)
  uint4 uv[4][4];
#pragma unroll
  for (int c=0;c<4;++c){
    if (c*16 < d){
#pragma unroll
      for (int g=0; g<4; ++g){
        if (c*16 + g*4 < d){
          int sj = __shfl(srcv[c], (g*4 + cq)*4);
          uv[c][g] = *(const uint4*)(hpack + (size_t)sj*64 + cl*4);
        }
      }
    }
  }
  // B) consume: alpha shuffles + FMAs (overlaps the in-flight loads)
#pragma unroll
  for (int c=0;c<4;++c){
    if (c*16 < d){
      const float ac = av4[c] * inv;   // 0 for invalid edges (exp(-inf))
#pragma unroll
      for (int g=0; g<4; ++g){
        if (c*16 + g*4 < d){
          float aj = __shfl(ac, (g*4 + cq)*4 + hsel);
          uint4 u  = uv[c][g];
          acc8[0] = fmaf(aj, bflo(u.x), acc8[0]);
          acc8[1] = fmaf(aj, bfhi(u.x), acc8[1]);
          acc8[2] = fmaf(aj, bflo(u.y), acc8[2]);
          acc8[3] = fmaf(aj, bfhi(u.y), acc8[3]);
          acc8[4] = fmaf(aj, bflo(u.z), acc8[4]);
          acc8[5] = fmaf(aj, bfhi(u.z), acc8[5]);
          acc8[6] = fmaf(aj, bflo(u.w), acc8[6]);
          acc8[7] = fmaf(aj, bfhi(u.w), acc8[7]);
        }
      }
    }
  }
  // tail (d > 64): statistically never for this graph; kept for correctness
  for (int c0=64; c0<d; c0+=16){
    int e = c0 + eL;
    int s2 = 0; float al = 0.f;
    if (e < d){
      s2 = csr[st + e];
      float e0 = asrc[s2*4 + h] + adh;
      float evv = (e0 > 0.f) ? e0 : 0.2f*e0;
      al = __expf(evv - mL) * inv;
    }
#pragma unroll
    for (int g=0; g<4; ++g){
      if (c0 + g*4 < d){
        int   sj = __shfl(s2, (g*4 + cq)*4);
        float aj = __shfl(al, (g*4 + cq)*4 + hsel);
        uint4 u  = *(const uint4*)(hpack + (size_t)sj*64 + cl*4);
        acc8[0] = fmaf(aj, bflo(u.x), acc8[0]);
        acc8[1] = fmaf(aj, bfhi(u.x), acc8[1]);
        acc8[2] = fmaf(aj, bflo(u.y), acc8[2]);
        acc8[3] = fmaf(aj, bfhi(u.y), acc8[3]);
        acc8[4] = fmaf(aj, bflo(u.z), acc8[4]);
        acc8[5] = fmaf(aj, bfhi(u.z), acc8[5]);
        acc8[6] = fmaf(aj, bflo(u.w), acc8[6]);
        acc8[7] = fmaf(aj, bfhi(u.w), acc8[7]);
      }
    }
  }

  // reduce the 4 row-groups (lanes differing in bits 4,5 hold same cols)
#pragma unroll
  for (int o=16;o<64;o<<=1){
#pragma unroll
    for (int k=0;k<8;++k) acc8[k] += __shfl_xor(acc8[k], o);
  }

  if (cq == 0){
    const float* bp = bias + layer*DD + cl*8;
    float4 b0 = *(const float4*)(bp);
    float4 b1 = *(const float4*)(bp + 4);
    float4 o0, o1;
    o0.x = siluf(acc8[0] + b0.x); o0.y = siluf(acc8[1] + b0.y);
    o0.z = siluf(acc8[2] + b0.z); o0.w = siluf(acc8[3] + b0.w);
    o1.x = siluf(acc8[4] + b1.x); o1.y = siluf(acc8[5] + b1.y);
    o1.z = siluf(acc8[6] + b1.z); o1.w = siluf(acc8[7] + b1.w);
    float* op = hout + (size_t)n*DD + cl*8;
    *(float4*)(op)     = o0;
    *(float4*)(op + 4) = o1;
  }
}

// ---------------- global_add_pool v2 (batch sorted): 256-row blocks,
// float4 loads, LDS-staged batch ids, register run-accumulate, boundary atomics
#define PROWS 256
__global__ __launch_bounds__(256) void pool_kernel(const float* __restrict__ h,
    const int* __restrict__ batch, float* __restrict__ pooled)
{
  __shared__ int gb[PROWS];
  const int t  = threadIdx.x;
  const int n0 = blockIdx.x * PROWS;
  {
    int n = n0 + t;
    gb[t] = (n < NN) ? batch[n] : -1;
  }
  __syncthreads();
  const int cq = t & 31;           // col quad: cols [cq*4, cq*4+4)
  const int rg = t >> 5;           // row group 0..7
  float4 sum = make_float4(0.f,0.f,0.f,0.f);
  int cur = -1;
#pragma unroll 4
  for (int k = 0; k < PROWS/8; ++k){
    int r = rg + k*8;
    int n = n0 + r;
    if (n >= NN) break;
    int g = gb[r];
    if (g != cur){
      if (cur >= 0){
        float* pp = pooled + cur*DD + cq*4;
        atomicAdd(pp+0, sum.x); atomicAdd(pp+1, sum.y);
        atomicAdd(pp+2, sum.z); atomicAdd(pp+3, sum.w);
      }
      cur = g; sum = make_float4(0.f,0.f,0.f,0.f);
    }
    float4 v = *(const float4*)(h + (size_t)n*DD + cq*4);
    sum.x += v.x; sum.y += v.y; sum.z += v.z; sum.w += v.w;
  }
  if (cur >= 0){
    float* pp = pooled + cur*DD + cq*4;
    atomicAdd(pp+0, sum.x); atomicAdd(pp+1, sum.y);
    atomicAdd(pp+2, sum.z); atomicAdd(pp+3, sum.w);
  }
}

// ---------------- KAN readout + log_softmax (1 block per graph) ----------------
__global__ __launch_bounds__(64) void readout_kernel(const float* __restrict__ pooled,
    const float* __restrict__ bw, const float* __restrict__ sw, const float* __restrict__ sc,
    float* __restrict__ out)
{
  int g = blockIdx.x, lane = threadIdx.x;
  float xa = pooled[g*DD + lane];
  float xb = pooled[g*DD + lane + 64];
  float fa[8], fb[8];
  kan_feats(xa, fa);
  kan_feats(xb, fb);
  float logits[NCL];
#pragma unroll
  for (int c=0;c<NCL;++c){
    int ia = c*DD + lane, ib = ia + 64;
    float sca = sc[ia], scb = sc[ib];
    float p = fa[0]*bw[ia] + fb[0]*bw[ib];
#pragma unroll
    for (int f=1;f<8;++f)
      p += fa[f]*sw[ia*7 + f-1]*sca + fb[f]*sw[ib*7 + f-1]*scb;
#pragma unroll
    for (int o=1;o<64;o<<=1) p += __shfl_xor(p, o);
    logits[c] = p;
  }
  float mx = logits[0];
#pragma unroll
  for (int c=1;c<NCL;++c) mx = fmaxf(mx, logits[c]);
  float lse = 0.f;
#pragma unroll
  for (int c=0;c<NCL;++c) lse += __expf(logits[c]-mx);
  lse = mx + logf(lse);
  if (lane < NCL){
    float v = 0.f;
#pragma unroll
    for (int c=0;c<NCL;++c) if (lane == c) v = logits[c] - lse;
    out[g*NCL + lane] = v;
  }
}

// ---------------- host ----------------
extern "C" void kernel_launch(void* const* d_in, const int* in_sizes, int n_in,
                              void* d_out, int out_size, void* d_ws, size_t ws_size,
                              hipStream_t stream)
{
  const float* x        = (const float*)d_in[0];
  const int*   ei       = (const int*)  d_in[1];
  const int*   batch    = (const int*)  d_in[2];
  const float* base_w   = (const float*)d_in[3];
  const float* spline_w = (const float*)d_in[4];
  const float* scaler   = (const float*)d_in[5];
  const float* att_src  = (const float*)d_in[6];
  const float* att_dst  = (const float*)d_in[7];
  const float* bias     = (const float*)d_in[8];
  const float* ro_bw    = (const float*)d_in[9];
  const float* ro_sw    = (const float*)d_in[10];
  const float* ro_sc    = (const float*)d_in[11];
  float* out = (float*)d_out;

  char* p = (char*)d_ws;
  auto alloc = [&](size_t bytes)->char* {
    char* r = p;
    p += (bytes + 255) & ~(size_t)255;
    return r;
  };
  unsigned int* hpack = (unsigned int*)alloc((size_t)50048*64*4);
  float* hbuf   = (float*)alloc((size_t)NN*DD*4);
  unsigned short* wfrag = (unsigned short*)alloc((size_t)3*131072*2);
  float* asrc   = (float*)alloc((size_t)NN*4*4);
  float* adst   = (float*)alloc((size_t)NN*4*4);
  float* pooled = (float*)alloc((size_t)NGR*DD*4);
  int*   deg    = (int*)alloc((size_t)NN*4);
  int*   offs   = (int*)alloc((size_t)NN*4);
  int*   csr    = (int*)alloc((size_t)ETOT*4);
  unsigned* tmp = (unsigned*)alloc((size_t)NBUK*TCAP*4);
  int*   bcur   = (int*)alloc((size_t)NBUK*4);

  hipMemsetAsync(bcur, 0, (size_t)NBUK*sizeof(int), stream);
  binpass_kernel<<<256, 256, 0, stream>>>(ei, bcur, tmp);
  scatter_kernel<<<NBUK,256, 0, stream>>>(tmp, bcur, offs, deg, csr);
  build_wfrag   <<<(3*128*1024)/256, 256, 0, stream>>>(base_w, spline_w, scaler, wfrag);

  const float* cur = x;
  for (int l=0; l<3; ++l){
    kan_gemm   <<<(NN+31)/32, 256, 0, stream>>>(cur, wfrag, att_src, att_dst,
                                                hpack, asrc, adst, l);
    attn_kernel<<<(NN+3)/4,   256, 0, stream>>>(hpack, asrc, adst, offs, deg, csr,
                                                bias, hbuf, l);
    cur = hbuf;
  }
  hipMemsetAsync(pooled, 0, (size_t)NGR*DD*sizeof(float), stream);
  pool_kernel   <<<(NN+255)/PROWS, 256, 0, stream>>>(hbuf, batch, pooled);
  readout_kernel<<<NGR, 64, 0, stream>>>(pooled, ro_bw, ro_sw, ro_sc, out);
}

// Round 6
// 379.154 us; speedup vs baseline: 1.0897x; 1.0897x over previous
//
#include <hip/hip_runtime.h>
#include <math.h>

#define NN 50000
#define EE 800000
#define ETOT (EE + NN)
#define NGR 64
#define DD 128
#define NCL 10

#define NBUK 256              // buckets (1 scatter block each -> 1 block/CU)
#define BNODES 196            // 256*196 = 50176 >= NN
#define P1GRID 1024           // binpass blocks (was 256 -> 12.5% occupancy)
#define P1CH 831              // ceil(ETOT/P1GRID)
#define TCAP 4608             // per-bucket tmp cap (mean 3329, sd ~58 -> +22 sigma)
#define P2CAP TCAP

typedef __attribute__((ext_vector_type(16))) float float16_t;
typedef __attribute__((ext_vector_type(8)))  __bf16 bf16x8;

// ---------------- device helpers ----------------
__device__ __forceinline__ float siluf(float x){ return x / (1.f + __expf(-x)); }

__device__ __forceinline__ unsigned f2bf(float f){
  union { float f; unsigned u; } v; v.f = f;
  unsigned r = v.u + 0x7fffu + ((v.u >> 16) & 1u);
  return (r >> 16) & 0xffffu;
}

__device__ __forceinline__ float bflo(unsigned u){ return __uint_as_float(u << 16); }
__device__ __forceinline__ float bfhi(unsigned u){ return __uint_as_float(u & 0xffff0000u); }

// 8 KAN features of scalar x: [silu(x), B0..B6] (float version for readout)
__device__ __forceinline__ void kan_feats(float x, float* f8){
  f8[0] = siluf(x);
  float u = 2.f*x + 5.f;
  int cell = -1;
  float n0=0.f,n1=0.f,n2=0.f,n3=0.f;
  if (u >= 0.f && u < 10.f){
    cell = (int)u;
    float t = u - (float)cell;
    float t2 = t*t, t3 = t2*t;
    float omt = 1.f - t;
    const float s6 = 1.f/6.f;
    n0 = t3*s6;
    n1 = s6*(1.f + 3.f*t + 3.f*t2 - 3.f*t3);
    n2 = s6*(4.f - 6.f*t2 + 3.f*t3);
    n3 = omt*omt*omt*s6;
  }
#pragma unroll
  for (int j=0;j<7;++j){
    int k = cell - j;
    float v = (k==0)?n0:((k==1)?n1:((k==2)?n2:((k==3)?n3:0.f)));
    f8[1+j] = v;
  }
}

// Packed bf16 A-fragment of scalar x: us[0..7] = [silu, B0..B6] via 64-bit shift.
__device__ __forceinline__ int4 kan_feats_pack(float x){
  unsigned sbf = f2bf(siluf(x));
  float u = 2.f*x + 5.f;
  bool valid = (u >= 0.f) && (u < 10.f);
  float uc = valid ? u : 0.f;
  int cell = (int)uc;
  float t = uc - (float)cell;
  float t2 = t*t, t3 = t2*t, omt = 1.f - t;
  const float s6 = 1.f/6.f;
  float n0 = t3*s6;
  float n1 = s6*(1.f + 3.f*t + 3.f*t2 - 3.f*t3);
  float n2 = s6*(4.f - 6.f*t2 + 3.f*t3);
  float n3 = omt*omt*omt*s6;
  unsigned p0=f2bf(n0), p1=f2bf(n1), p2=f2bf(n2), p3=f2bf(n3);
  unsigned long long P = ((unsigned long long)(p1 | (p0<<16)) << 32)
                       |  (unsigned long long)(p3 | (p2<<16));
  int sh = cell*16 - 48;
  unsigned long long shl    = P << (sh & 63);
  unsigned long long shrhi  = P >> ((64 - sh) & 63);
  unsigned long long shllo2 = P << ((sh - 64) & 63);
  unsigned long long shrlo  = P >> ((-sh) & 63);
  unsigned long long F0, F1;
  if (sh < 0)       { F0 = shrlo; F1 = 0ull; }
  else if (sh < 64) { F0 = shl;   F1 = (sh==0)? 0ull : shrhi; }
  else              { F0 = 0ull;  F1 = shllo2; }
  if (!valid){ F0 = 0ull; F1 = 0ull; }
  unsigned w0 = ((unsigned)(F0 & 0xffffull) << 16) | sbf;
  unsigned w1 = (unsigned)((F0 >> 16) & 0xffffffffull);
  unsigned w2 = (unsigned)((F0 >> 48) & 0xffffull) | (((unsigned)(F1 & 0xffffull)) << 16);
  unsigned w3 = (unsigned)((F1 >> 16) & 0xffffffffull);
  return make_int4((int)w0,(int)w1,(int)w2,(int)w3);
}

// ---------------- CSR build v4: 2 kernels, bucket-strided tmp, scaled grids ----
// Pass 1 (multisplit): 1024 blocks, each owns 831 edges; LDS-sorts by dst-bucket
// (256 buckets of 196 nodes) and flushes bucket-contiguous runs into
// tmp[b*TCAP + rel], reserving with ONE global atomic per (block,bucket).
// tmp entry: (bucket<<24) | (dstLocal<<16) | src   (b<256, dl<196, src<65536)
__global__ __launch_bounds__(256) void binpass_kernel(const int* __restrict__ ei,
                                                      int* __restrict__ bcur,
                                                      unsigned* __restrict__ tmp){
  __shared__ int cnt[NBUK], lexcl[NBUK], gbase[NBUK], lcur[NBUK];
  __shared__ int sc[NBUK];
  __shared__ unsigned entries[P1CH + 1];
  const int t = threadIdx.x;
  const int e0 = blockIdx.x * P1CH;
  int e1 = e0 + P1CH; if (e1 > ETOT) e1 = ETOT;
  const int total = e1 - e0;

  cnt[t] = 0; lcur[t] = 0;
  __syncthreads();

  // pass A: bucket histogram
  for (int e = e0 + t; e < e1; e += 256){
    int dst = (e < EE) ? ei[EE + e] : (e - EE);
    int b = dst / BNODES;
    atomicAdd(&cnt[b], 1);
  }
  __syncthreads();

  // exclusive scan of cnt over 256 buckets (Hillis-Steele, in place)
  sc[t] = cnt[t];
  __syncthreads();
  for (int o=1;o<NBUK;o<<=1){
    int v = (t >= o) ? sc[t - o] : 0;
    __syncthreads();
    sc[t] += v;
    __syncthreads();
  }
  lexcl[t] = sc[t] - cnt[t];
  __syncthreads();

  // reserve per-bucket chunks (bcur starts at 0)
  if (cnt[t] > 0) gbase[t] = atomicAdd(&bcur[t], cnt[t]);
  __syncthreads();

  // pass B: re-read and place into LDS sorted-by-bucket
  for (int e = e0 + t; e < e1; e += 256){
    int src, dst;
    if (e < EE){ src = ei[e]; dst = ei[EE + e]; } else { src = e - EE; dst = src; }
    int b = dst / BNODES;
    int dl = dst - b*BNODES;
    int r = lexcl[b] + atomicAdd(&lcur[b], 1);
    entries[r] = ((unsigned)b << 24) | ((unsigned)dl << 16) | (unsigned)src;
  }
  __syncthreads();

  // flush: consecutive slots -> consecutive tmp positions within a bucket
  for (int s = t; s < total; s += 256){
    unsigned en = entries[s];
    int b = en >> 24;
    int rel = gbase[b] + (s - lexcl[b]);
    if (rel < TCAP) tmp[(size_t)b*TCAP + rel] = en;
  }
}

// Pass 2: one block per bucket (256 blocks = 1/CU). Derives bucket base from the
// 256 bucket counts (LDS reduce), builds per-dst histogram+scan, writes offs/deg,
// then groups the bucket by dst in LDS and writes the csr window coalesced.
__global__ __launch_bounds__(256) void scatter_kernel(const unsigned* __restrict__ tmp,
                                                      const int* __restrict__ bcur,
                                                      int* __restrict__ offs,
                                                      int* __restrict__ deg,
                                                      int* __restrict__ csr){
  __shared__ unsigned sbuf[P2CAP];
  __shared__ int dcnt[BNODES+1], dscan[BNODES+1], dcur[BNODES+1];
  __shared__ int sA[256], sB[256];
  const int t = threadIdx.x;
  const int b = blockIdx.x;
  const int lo = b * BNODES;

  // bucket base = sum of counts of buckets < b (tree reduce over 256)
  sA[t] = (t < b) ? bcur[t] : 0;
  __syncthreads();
  for (int o=128;o>=1;o>>=1){ if (t < o) sA[t] += sA[t+o]; __syncthreads(); }
  const int base = sA[0];
  const int cntb_raw = bcur[b];
  const int cntb = (cntb_raw < TCAP) ? cntb_raw : TCAP;
  const unsigned* tw = tmp + (size_t)b*TCAP;
  __syncthreads();

  if (t < BNODES+1){ dcnt[t] = 0; dcur[t] = 0; }
  __syncthreads();
  for (int i = t; i < cntb; i += 256){
    int dl = (tw[i] >> 16) & 0xFF;
    atomicAdd(&dcnt[dl], 1);
  }
  __syncthreads();

  // exclusive scan over 197 counters (padded to 256, double-buffered H-S)
  sA[t] = (t < BNODES+1) ? dcnt[t] : 0;
  __syncthreads();
  int* sp = sA; int* dp = sB;
  for (int o=1;o<256;o<<=1){
    dp[t] = sp[t] + ((t >= o) ? sp[t - o] : 0);
    __syncthreads();
    int* tpp = sp; sp = dp; dp = tpp;
  }
  if (t < BNODES+1) dscan[t] = sp[t] - dcnt[t];
  __syncthreads();

  // per-node offsets + degrees
  if (t < BNODES){
    int node = lo + t;
    if (node < NN){ offs[node] = base + dscan[t]; deg[node] = dcnt[t]; }
  }

  // LDS scatter by dstLocal, then fully-coalesced csr write
  for (int i = t; i < cntb; i += 256){
    unsigned en = tw[i];
    int dl = (en >> 16) & 0xFF;
    int r = dscan[dl] + atomicAdd(&dcur[dl], 1);
    sbuf[r] = en & 0xFFFFu;
  }
  __syncthreads();
  for (int i = t; i < cntb; i += 256) csr[base + i] = (int)sbuf[i];
}

// ---------------- fold weights into bf16, MFMA-fragment order ----------------
__global__ void build_wfrag(const float* __restrict__ bw, const float* __restrict__ sw,
                            const float* __restrict__ sc, unsigned short* __restrict__ wfrag){
  int idx = blockIdx.x*256 + threadIdx.x;
  if (idx >= 3*128*1024) return;
  int k = idx & 1023;
  int o = (idx >> 10) & 127;
  int l = idx >> 17;
  int i = k >> 3, f = k & 7;
  int oi = (l*DD + o)*DD + i;
  float w = (f == 0) ? bw[oi] : sw[oi*7 + (f-1)] * sc[oi];
  int s = k >> 6;
  int sl = (k >> 4) & 3, half = (k >> 3) & 1, j = k & 7;
  int ntile = o >> 5, n = o & 31;
  int dst = l*131072 + s*8192 + (((ntile*4 + sl)*64) + half*32 + n)*8 + j;
  wfrag[dst] = (unsigned short)f2bf(w);
}

// ---------------- fused KAN feats + GEMM + pack + attention logits ----------------
// 32-row tile / 1563 blocks: LDS 25 KB (xs 32x132 f32 + Afrag 2x2048 bf16).
// launch_bounds(256,4): VGPR cap 128 so the Bc/Bn double-buffer + acc stay in
// registers. LDS caps residency at 6 blocks/CU.
__global__ __launch_bounds__(256, 4) void kan_gemm(const float* __restrict__ xin,
                                                const unsigned short* __restrict__ wfrag,
                                                const float* __restrict__ attS,
                                                const float* __restrict__ attD,
                                                unsigned int* __restrict__ hpack,
                                                float* __restrict__ asrc,
                                                float* __restrict__ adst, int layer)
{
  __shared__ __align__(16) float xs[32*132];               // 16896 B (reused as hs)
  __shared__ __align__(16) unsigned short Afrag[2][2048];  // 8192 B
  const int t    = threadIdx.x;
  const int lane = t & 63;
  const int w    = t >> 6;          // wave -> output col tile w*32
  const int half = lane >> 5;
  const int mn   = lane & 31;
  const int row0 = blockIdx.x * 32;
  const int r_my = t & 31;          // row this thread packs
  const int j_my = t >> 5;          // col-in-step this thread packs (0..7)
  const unsigned short* wl = wfrag + layer*131072;

  // stage x rows [row0, row0+32) x 128 cols, float4-coalesced
#pragma unroll
  for (int q=0;q<4;++q){
    int p = q*256 + t;
    int r = p >> 5, c4 = p & 31;
    int grow = row0 + r;
    float4 v = make_float4(0.f,0.f,0.f,0.f);
    if (grow < NN) v = *(const float4*)(xin + (size_t)grow*DD + c4*4);
    *(float4*)(&xs[r*132 + c4*4]) = v;
  }
  __syncthreads();

  float16_t acc;
#pragma unroll
  for (int i=0;i<16;++i) acc[i]=0.f;

  int4 Bc[4], Bn[4];
#pragma unroll
  for (int sl=0;sl<4;++sl)
    Bc[sl] = *(const int4*)(wl + ((w*4+sl)*64 + lane)*8);

  // Afrag slot for (col j, row r) = ((j*32 + r)*8) ushorts
  const int fo = (j_my*32 + r_my)*8;
  {
    int4 P = kan_feats_pack(xs[r_my*132 + j_my]);
    *(int4*)(&Afrag[0][fo]) = P;
  }
  __syncthreads();

  for (int s=0; s<16; ++s){
    if (s < 15){
      const unsigned short* wsrc = wl + (s+1)*8192;
#pragma unroll
      for (int sl=0;sl<4;++sl)
        Bn[sl] = *(const int4*)(wsrc + ((w*4+sl)*64 + lane)*8);
      int4 P = kan_feats_pack(xs[r_my*132 + (s+1)*8 + j_my]);
      *(int4*)(&Afrag[(s+1)&1][fo]) = P;
    }
    const unsigned short* A = Afrag[s&1];
#pragma unroll
    for (int sl=0; sl<4; ++sl){
      int4 ai = *(const int4*)(A + ((sl*2 + half)*32 + mn)*8);
      bf16x8 b = __builtin_bit_cast(bf16x8, Bc[sl]);
      acc = __builtin_amdgcn_mfma_f32_32x32x16_bf16(__builtin_bit_cast(bf16x8, ai), b, acc, 0, 0, 0);
    }
#pragma unroll
    for (int sl=0;sl<4;++sl) Bc[sl] = Bn[sl];
    __syncthreads();
  }

  // epilogue: bf16-pack into LDS (reuse xs), then coalesced hpack write + att logits
  unsigned short* hs = (unsigned short*)xs;
#pragma unroll
  for (int reg=0; reg<16; ++reg){
    int row = (reg&3) + 8*(reg>>2) + 4*half;
    int col = w*32 + mn;
    hs[row*136 + col] = (unsigned short)f2bf(acc[reg]);
  }
  __syncthreads();
#pragma unroll
  for (int q=0;q<2;++q){
    int p = q*256 + t;
    int row = p >> 4, u4 = p & 15;
    uint4 v = *(const uint4*)((const unsigned int*)(hs + row*136) + u4*4);
    int grow = row0 + row;
    if (grow < NN) *(uint4*)(hpack + (size_t)grow*64 + u4*4) = v;
  }
  if (t < 128){
    int r = t >> 2, h = t & 3;
    const unsigned* hrow = (const unsigned*)(hs + r*136) + h*16;
    const float* ws = attS + (layer*4 + h)*32;
    const float* wd = attD + (layer*4 + h)*32;
    float ss = 0.f, sd = 0.f;
#pragma unroll
    for (int j=0;j<16;++j){
      unsigned u = hrow[j];
      float flo = __uint_as_float(u << 16);
      float fhi = __uint_as_float(u & 0xffff0000u);
      ss += flo*ws[2*j] + fhi*ws[2*j+1];
      sd += flo*wd[2*j] + fhi*wd[2*j+1];
    }
    int grow = row0 + r;
    if (grow < NN){ asrc[grow*4 + h] = ss; adst[grow*4 + h] = sd; }
  }
}

// ---------------- GAT aggregation v6 (REVERT of v7: issue-early regressed via
// occupancy 64->36% at VGPR 52; interleaved load/FMA + ~20 waves/CU is the
// measured optimum, 46.3us): uint4 gathers, alpha=0 tail masking, xor-reduce ----
__global__ __launch_bounds__(256) void attn_kernel(
    const unsigned int* __restrict__ hpack, const float* __restrict__ asrc, const float* __restrict__ adst,
    const int* __restrict__ offs, const int* __restrict__ deg, const int* __restrict__ csr,
    const float* __restrict__ bias, float* __restrict__ hout, int layer)
{
  const int wave = threadIdx.x >> 6;
  const int lane = threadIdx.x & 63;
  const int n = blockIdx.x*4 + wave;
  if (n >= NN) return;
  const int st = offs[n];
  const int d  = deg[n];
  const int eL = lane >> 2, h = lane & 3;
  const float adh = adst[n*4 + h];

  // ---- phase 1: logits, running max ----
  int   srcv[4];
  float ev[4];
  float mL = -3.4e38f;
#pragma unroll
  for (int c=0;c<4;++c){
    srcv[c] = 0; ev[c] = -3.4e38f;
    if (c*16 < d){
      int e = c*16 + eL;
      if (e < d){
        int s2 = csr[st + e];
        srcv[c] = s2;
        float e0 = asrc[s2*4 + h] + adh;
        ev[c] = (e0 > 0.f) ? e0 : 0.2f*e0;
        mL = fmaxf(mL, ev[c]);
      }
    }
  }
  for (int c=64; c<d; c+=16){
    int e = c + eL;
    if (e < d){
      int s2 = csr[st + e];
      float e0 = asrc[s2*4 + h] + adh;
      float evv = (e0 > 0.f) ? e0 : 0.2f*e0;
      mL = fmaxf(mL, evv);
    }
  }
#pragma unroll
  for (int o=4;o<64;o<<=1) mL = fmaxf(mL, __shfl_xor(mL, o));

  // ---- phase 2: softmax denominator ----
  float av4[4];
  float sL = 0.f;
#pragma unroll
  for (int c=0;c<4;++c){ av4[c] = __expf(ev[c] - mL); sL += av4[c]; }
  for (int c=64; c<d; c+=16){
    int e = c + eL;
    if (e < d){
      int s2 = csr[st + e];
      float e0 = asrc[s2*4 + h] + adh;
      float evv = (e0 > 0.f) ? e0 : 0.2f*e0;
      sL += __expf(evv - mL);
    }
  }
#pragma unroll
  for (int o=4;o<64;o<<=1) sL += __shfl_xor(sL, o);
  const float inv = 1.f/(sL + 1e-16f);

  // ---- phase 3: weighted gather, uint4 layout ----
  // lane covers cols [8*cl, 8*cl+8) of row (g*4 + cq) in each load group
  const int cq   = lane >> 4;      // row-in-group 0..3
  const int cl   = lane & 15;      // col-quad 0..15
  const int hsel = cl >> 2;        // head owning my cols
  float acc8[8];
#pragma unroll
  for (int k=0;k<8;++k) acc8[k] = 0.f;

#pragma unroll
  for (int c=0;c<4;++c){
    if (c*16 < d){
      float ac = av4[c] * inv;     // 0 for invalid edges (exp(-inf))
#pragma unroll
      for (int g=0; g<4; ++g){
        if (c*16 + g*4 < d){
          int   sj = __shfl(srcv[c], (g*4 + cq)*4);
          float aj = __shfl(ac,      (g*4 + cq)*4 + hsel);
          uint4 u  = *(const uint4*)(hpack + (size_t)sj*64 + cl*4);
          acc8[0] = fmaf(aj, bflo(u.x), acc8[0]);
          acc8[1] = fmaf(aj, bfhi(u.x), acc8[1]);
          acc8[2] = fmaf(aj, bflo(u.y), acc8[2]);
          acc8[3] = fmaf(aj, bfhi(u.y), acc8[3]);
          acc8[4] = fmaf(aj, bflo(u.z), acc8[4]);
          acc8[5] = fmaf(aj, bfhi(u.z), acc8[5]);
          acc8[6] = fmaf(aj, bflo(u.w), acc8[6]);
          acc8[7] = fmaf(aj, bfhi(u.w), acc8[7]);
        }
      }
    }
  }
  // tail (d > 64): same uint4 pattern, logits recomputed per 16-edge chunk
  for (int c0=64; c0<d; c0+=16){
    int e = c0 + eL;
    int s2 = 0; float al = 0.f;
    if (e < d){
      s2 = csr[st + e];
      float e0 = asrc[s2*4 + h] + adh;
      float evv = (e0 > 0.f) ? e0 : 0.2f*e0;
      al = __expf(evv - mL) * inv;
    }
#pragma unroll
    for (int g=0; g<4; ++g){
      if (c0 + g*4 < d){
        int   sj = __shfl(s2, (g*4 + cq)*4);
        float aj = __shfl(al, (g*4 + cq)*4 + hsel);
        uint4 u  = *(const uint4*)(hpack + (size_t)sj*64 + cl*4);
        acc8[0] = fmaf(aj, bflo(u.x), acc8[0]);
        acc8[1] = fmaf(aj, bfhi(u.x), acc8[1]);
        acc8[2] = fmaf(aj, bflo(u.y), acc8[2]);
        acc8[3] = fmaf(aj, bfhi(u.y), acc8[3]);
        acc8[4] = fmaf(aj, bflo(u.z), acc8[4]);
        acc8[5] = fmaf(aj, bfhi(u.z), acc8[5]);
        acc8[6] = fmaf(aj, bflo(u.w), acc8[6]);
        acc8[7] = fmaf(aj, bfhi(u.w), acc8[7]);
      }
    }
  }

  // reduce the 4 row-groups (lanes differing in bits 4,5 hold same cols)
#pragma unroll
  for (int o=16;o<64;o<<=1){
#pragma unroll
    for (int k=0;k<8;++k) acc8[k] += __shfl_xor(acc8[k], o);
  }

  if (cq == 0){
    const float* bp = bias + layer*DD + cl*8;
    float4 b0 = *(const float4*)(bp);
    float4 b1 = *(const float4*)(bp + 4);
    float4 o0, o1;
    o0.x = siluf(acc8[0] + b0.x); o0.y = siluf(acc8[1] + b0.y);
    o0.z = siluf(acc8[2] + b0.z); o0.w = siluf(acc8[3] + b0.w);
    o1.x = siluf(acc8[4] + b1.x); o1.y = siluf(acc8[5] + b1.y);
    o1.z = siluf(acc8[6] + b1.z); o1.w = siluf(acc8[7] + b1.w);
    float* op = hout + (size_t)n*DD + cl*8;
    *(float4*)(op)     = o0;
    *(float4*)(op + 4) = o1;
  }
}

// ---------------- global_add_pool v2 (batch sorted): 256-row blocks,
// float4 loads, LDS-staged batch ids, register run-accumulate, boundary atomics
#define PROWS 256
__global__ __launch_bounds__(256) void pool_kernel(const float* __restrict__ h,
    const int* __restrict__ batch, float* __restrict__ pooled)
{
  __shared__ int gb[PROWS];
  const int t  = threadIdx.x;
  const int n0 = blockIdx.x * PROWS;
  {
    int n = n0 + t;
    gb[t] = (n < NN) ? batch[n] : -1;
  }
  __syncthreads();
  const int cq = t & 31;           // col quad: cols [cq*4, cq*4+4)
  const int rg = t >> 5;           // row group 0..7
  float4 sum = make_float4(0.f,0.f,0.f,0.f);
  int cur = -1;
#pragma unroll 4
  for (int k = 0; k < PROWS/8; ++k){
    int r = rg + k*8;
    int n = n0 + r;
    if (n >= NN) break;
    int g = gb[r];
    if (g != cur){
      if (cur >= 0){
        float* pp = pooled + cur*DD + cq*4;
        atomicAdd(pp+0, sum.x); atomicAdd(pp+1, sum.y);
        atomicAdd(pp+2, sum.z); atomicAdd(pp+3, sum.w);
      }
      cur = g; sum = make_float4(0.f,0.f,0.f,0.f);
    }
    float4 v = *(const float4*)(h + (size_t)n*DD + cq*4);
    sum.x += v.x; sum.y += v.y; sum.z += v.z; sum.w += v.w;
  }
  if (cur >= 0){
    float* pp = pooled + cur*DD + cq*4;
    atomicAdd(pp+0, sum.x); atomicAdd(pp+1, sum.y);
    atomicAdd(pp+2, sum.z); atomicAdd(pp+3, sum.w);
  }
}

// ---------------- KAN readout + log_softmax (1 block per graph) ----------------
__global__ __launch_bounds__(64) void readout_kernel(const float* __restrict__ pooled,
    const float* __restrict__ bw, const float* __restrict__ sw, const float* __restrict__ sc,
    float* __restrict__ out)
{
  int g = blockIdx.x, lane = threadIdx.x;
  float xa = pooled[g*DD + lane];
  float xb = pooled[g*DD + lane + 64];
  float fa[8], fb[8];
  kan_feats(xa, fa);
  kan_feats(xb, fb);
  float logits[NCL];
#pragma unroll
  for (int c=0;c<NCL;++c){
    int ia = c*DD + lane, ib = ia + 64;
    float sca = sc[ia], scb = sc[ib];
    float p = fa[0]*bw[ia] + fb[0]*bw[ib];
#pragma unroll
    for (int f=1;f<8;++f)
      p += fa[f]*sw[ia*7 + f-1]*sca + fb[f]*sw[ib*7 + f-1]*scb;
#pragma unroll
    for (int o=1;o<64;o<<=1) p += __shfl_xor(p, o);
    logits[c] = p;
  }
  float mx = logits[0];
#pragma unroll
  for (int c=1;c<NCL;++c) mx = fmaxf(mx, logits[c]);
  float lse = 0.f;
#pragma unroll
  for (int c=0;c<NCL;++c) lse += __expf(logits[c]-mx);
  lse = mx + logf(lse);
  if (lane < NCL){
    float v = 0.f;
#pragma unroll
    for (int c=0;c<NCL;++c) if (lane == c) v = logits[c] - lse;
    out[g*NCL + lane] = v;
  }
}

// ---------------- host ----------------
extern "C" void kernel_launch(void* const* d_in, const int* in_sizes, int n_in,
                              void* d_out, int out_size, void* d_ws, size_t ws_size,
                              hipStream_t stream)
{
  const float* x        = (const float*)d_in[0];
  const int*   ei       = (const int*)  d_in[1];
  const int*   batch    = (const int*)  d_in[2];
  const float* base_w   = (const float*)d_in[3];
  const float* spline_w = (const float*)d_in[4];
  const float* scaler   = (const float*)d_in[5];
  const float* att_src  = (const float*)d_in[6];
  const float* att_dst  = (const float*)d_in[7];
  const float* bias     = (const float*)d_in[8];
  const float* ro_bw    = (const float*)d_in[9];
  const float* ro_sw    = (const float*)d_in[10];
  const float* ro_sc    = (const float*)d_in[11];
  float* out = (float*)d_out;

  char* p = (char*)d_ws;
  auto alloc = [&](size_t bytes)->char* {
    char* r = p;
    p += (bytes + 255) & ~(size_t)255;
    return r;
  };
  unsigned int* hpack = (unsigned int*)alloc((size_t)50048*64*4);
  float* hbuf   = (float*)alloc((size_t)NN*DD*4);
  unsigned short* wfrag = (unsigned short*)alloc((size_t)3*131072*2);
  float* asrc   = (float*)alloc((size_t)NN*4*4);
  float* adst   = (float*)alloc((size_t)NN*4*4);
  float* pooled = (float*)alloc((size_t)NGR*DD*4);
  int*   deg    = (int*)alloc((size_t)NN*4);
  int*   offs   = (int*)alloc((size_t)NN*4);
  int*   csr    = (int*)alloc((size_t)ETOT*4);
  unsigned* tmp = (unsigned*)alloc((size_t)NBUK*TCAP*4);
  int*   bcur   = (int*)alloc((size_t)NBUK*4);

  hipMemsetAsync(bcur, 0, (size_t)NBUK*sizeof(int), stream);
  binpass_kernel<<<P1GRID, 256, 0, stream>>>(ei, bcur, tmp);
  scatter_kernel<<<NBUK,  256, 0, stream>>>(tmp, bcur, offs, deg, csr);
  build_wfrag   <<<(3*128*1024)/256, 256, 0, stream>>>(base_w, spline_w, scaler, wfrag);

  const float* cur = x;
  for (int l=0; l<3; ++l){
    kan_gemm   <<<(NN+31)/32, 256, 0, stream>>>(cur, wfrag, att_src, att_dst,
                                                hpack, asrc, adst, l);
    attn_kernel<<<(NN+3)/4,   256, 0, stream>>>(hpack, asrc, adst, offs, deg, csr,
                                                bias, hbuf, l);
    cur = hbuf;
  }
  hipMemsetAsync(pooled, 0, (size_t)NGR*DD*sizeof(float), stream);
  pool_kernel   <<<(NN+255)/PROWS, 256, 0, stream>>>(hbuf, batch, pooled);
  readout_kernel<<<NGR, 64, 0, stream>>>(pooled, ro_bw, ro_sw, ro_sc, out);
}

// Round 8
// 376.252 us; speedup vs baseline: 1.0981x; 1.0077x over previous
//
#include <hip/hip_runtime.h>
#include <math.h>

#define NN 50000
#define EE 800000
#define ETOT (EE + NN)
#define NGR 64
#define DD 128
#define NCL 10

#define NBUK 256              // buckets (1 scatter block each -> 1 block/CU)
#define BNODES 196            // 256*196 = 50176 >= NN
#define P1GRID 1024           // binpass blocks
#define P1CH 831              // ceil(ETOT/P1GRID)
#define TCAP 4608             // per-bucket tmp cap (mean 3329, sd ~58 -> +22 sigma)
#define P2CAP TCAP

typedef __attribute__((ext_vector_type(16))) float float16_t;
typedef __attribute__((ext_vector_type(8)))  __bf16 bf16x8;

// ---------------- device helpers ----------------
__device__ __forceinline__ float siluf(float x){ return x / (1.f + __expf(-x)); }

__device__ __forceinline__ unsigned f2bf(float f){
  union { float f; unsigned u; } v; v.f = f;
  unsigned r = v.u + 0x7fffu + ((v.u >> 16) & 1u);
  return (r >> 16) & 0xffffu;
}

__device__ __forceinline__ float bflo(unsigned u){ return __uint_as_float(u << 16); }
__device__ __forceinline__ float bfhi(unsigned u){ return __uint_as_float(u & 0xffff0000u); }

// 8 KAN features of scalar x: [silu(x), B0..B6] (float version for readout)
__device__ __forceinline__ void kan_feats(float x, float* f8){
  f8[0] = siluf(x);
  float u = 2.f*x + 5.f;
  int cell = -1;
  float n0=0.f,n1=0.f,n2=0.f,n3=0.f;
  if (u >= 0.f && u < 10.f){
    cell = (int)u;
    float t = u - (float)cell;
    float t2 = t*t, t3 = t2*t;
    float omt = 1.f - t;
    const float s6 = 1.f/6.f;
    n0 = t3*s6;
    n1 = s6*(1.f + 3.f*t + 3.f*t2 - 3.f*t3);
    n2 = s6*(4.f - 6.f*t2 + 3.f*t3);
    n3 = omt*omt*omt*s6;
  }
#pragma unroll
  for (int j=0;j<7;++j){
    int k = cell - j;
    float v = (k==0)?n0:((k==1)?n1:((k==2)?n2:((k==3)?n3:0.f)));
    f8[1+j] = v;
  }
}

// Packed bf16 A-fragment of scalar x: us[0..7] = [silu, B0..B6] via 64-bit shift.
// NOTE: manual f2bf RTNE only — round-7's v_cvt_pk_bf16_f32 inline asm produced
// NaN on this toolchain (bundled change, unproven micro-semantics; do not reuse
// without single-change isolation).
__device__ __forceinline__ int4 kan_feats_pack(float x){
  unsigned sbf = f2bf(siluf(x));
  float u = 2.f*x + 5.f;
  bool valid = (u >= 0.f) && (u < 10.f);
  float uc = valid ? u : 0.f;
  int cell = (int)uc;
  float t = uc - (float)cell;
  float t2 = t*t, t3 = t2*t, omt = 1.f - t;
  const float s6 = 1.f/6.f;
  float n0 = t3*s6;
  float n1 = s6*(1.f + 3.f*t + 3.f*t2 - 3.f*t3);
  float n2 = s6*(4.f - 6.f*t2 + 3.f*t3);
  float n3 = omt*omt*omt*s6;
  unsigned p0=f2bf(n0), p1=f2bf(n1), p2=f2bf(n2), p3=f2bf(n3);
  unsigned long long P = ((unsigned long long)(p1 | (p0<<16)) << 32)
                       |  (unsigned long long)(p3 | (p2<<16));
  int sh = cell*16 - 48;
  unsigned long long shl    = P << (sh & 63);
  unsigned long long shrhi  = P >> ((64 - sh) & 63);
  unsigned long long shllo2 = P << ((sh - 64) & 63);
  unsigned long long shrlo  = P >> ((-sh) & 63);
  unsigned long long F0, F1;
  if (sh < 0)       { F0 = shrlo; F1 = 0ull; }
  else if (sh < 64) { F0 = shl;   F1 = (sh==0)? 0ull : shrhi; }
  else              { F0 = 0ull;  F1 = shllo2; }
  if (!valid){ F0 = 0ull; F1 = 0ull; }
  unsigned w0 = ((unsigned)(F0 & 0xffffull) << 16) | sbf;
  unsigned w1 = (unsigned)((F0 >> 16) & 0xffffffffull);
  unsigned w2 = (unsigned)((F0 >> 48) & 0xffffull) | (((unsigned)(F1 & 0xffffull)) << 16);
  unsigned w3 = (unsigned)((F1 >> 16) & 0xffffffffull);
  return make_int4((int)w0,(int)w1,(int)w2,(int)w3);
}

// ---------------- CSR build v4: 2 kernels, bucket-strided tmp ----------------
// tmp entry: (bucket<<24) | (dstLocal<<16) | src   (b<256, dl<196, src<65536)
__global__ __launch_bounds__(256) void binpass_kernel(const int* __restrict__ ei,
                                                      int* __restrict__ bcur,
                                                      unsigned* __restrict__ tmp){
  __shared__ int cnt[NBUK], lexcl[NBUK], gbase[NBUK], lcur[NBUK];
  __shared__ int sc[NBUK];
  __shared__ unsigned entries[P1CH + 1];
  const int t = threadIdx.x;
  const int e0 = blockIdx.x * P1CH;
  int e1 = e0 + P1CH; if (e1 > ETOT) e1 = ETOT;
  const int total = e1 - e0;

  cnt[t] = 0; lcur[t] = 0;
  __syncthreads();

  // pass A: bucket histogram
  for (int e = e0 + t; e < e1; e += 256){
    int dst = (e < EE) ? ei[EE + e] : (e - EE);
    int b = dst / BNODES;
    atomicAdd(&cnt[b], 1);
  }
  __syncthreads();

  // exclusive scan of cnt over 256 buckets (Hillis-Steele, in place)
  sc[t] = cnt[t];
  __syncthreads();
  for (int o=1;o<NBUK;o<<=1){
    int v = (t >= o) ? sc[t - o] : 0;
    __syncthreads();
    sc[t] += v;
    __syncthreads();
  }
  lexcl[t] = sc[t] - cnt[t];
  __syncthreads();

  // reserve per-bucket chunks (bcur starts at 0)
  if (cnt[t] > 0) gbase[t] = atomicAdd(&bcur[t], cnt[t]);
  __syncthreads();

  // pass B: re-read and place into LDS sorted-by-bucket
  for (int e = e0 + t; e < e1; e += 256){
    int src, dst;
    if (e < EE){ src = ei[e]; dst = ei[EE + e]; } else { src = e - EE; dst = src; }
    int b = dst / BNODES;
    int dl = dst - b*BNODES;
    int r = lexcl[b] + atomicAdd(&lcur[b], 1);
    entries[r] = ((unsigned)b << 24) | ((unsigned)dl << 16) | (unsigned)src;
  }
  __syncthreads();

  // flush: consecutive slots -> consecutive tmp positions within a bucket
  for (int s = t; s < total; s += 256){
    unsigned en = entries[s];
    int b = en >> 24;
    int rel = gbase[b] + (s - lexcl[b]);
    if (rel < TCAP) tmp[(size_t)b*TCAP + rel] = en;
  }
}

// Pass 2: one block per bucket; derives bucket base, per-dst histogram+scan,
// writes offs/deg, then groups by dst in LDS and writes csr coalesced.
__global__ __launch_bounds__(256) void scatter_kernel(const unsigned* __restrict__ tmp,
                                                      const int* __restrict__ bcur,
                                                      int* __restrict__ offs,
                                                      int* __restrict__ deg,
                                                      int* __restrict__ csr){
  __shared__ unsigned sbuf[P2CAP];
  __shared__ int dcnt[BNODES+1], dscan[BNODES+1], dcur[BNODES+1];
  __shared__ int sA[256], sB[256];
  const int t = threadIdx.x;
  const int b = blockIdx.x;
  const int lo = b * BNODES;

  // bucket base = sum of counts of buckets < b (tree reduce over 256)
  sA[t] = (t < b) ? bcur[t] : 0;
  __syncthreads();
  for (int o=128;o>=1;o>>=1){ if (t < o) sA[t] += sA[t+o]; __syncthreads(); }
  const int base = sA[0];
  const int cntb_raw = bcur[b];
  const int cntb = (cntb_raw < TCAP) ? cntb_raw : TCAP;
  const unsigned* tw = tmp + (size_t)b*TCAP;
  __syncthreads();

  if (t < BNODES+1){ dcnt[t] = 0; dcur[t] = 0; }
  __syncthreads();
  for (int i = t; i < cntb; i += 256){
    int dl = (tw[i] >> 16) & 0xFF;
    atomicAdd(&dcnt[dl], 1);
  }
  __syncthreads();

  // exclusive scan over 197 counters (padded to 256, double-buffered H-S)
  sA[t] = (t < BNODES+1) ? dcnt[t] : 0;
  __syncthreads();
  int* sp = sA; int* dp = sB;
  for (int o=1;o<256;o<<=1){
    dp[t] = sp[t] + ((t >= o) ? sp[t - o] : 0);
    __syncthreads();
    int* tpp = sp; sp = dp; dp = tpp;
  }
  if (t < BNODES+1) dscan[t] = sp[t] - dcnt[t];
  __syncthreads();

  // per-node offsets + degrees
  if (t < BNODES){
    int node = lo + t;
    if (node < NN){ offs[node] = base + dscan[t]; deg[node] = dcnt[t]; }
  }

  // LDS scatter by dstLocal, then fully-coalesced csr write
  for (int i = t; i < cntb; i += 256){
    unsigned en = tw[i];
    int dl = (en >> 16) & 0xFF;
    int r = dscan[dl] + atomicAdd(&dcur[dl], 1);
    sbuf[r] = en & 0xFFFFu;
  }
  __syncthreads();
  for (int i = t; i < cntb; i += 256) csr[base + i] = (int)sbuf[i];
}

// ---------------- fold weights into bf16, MFMA-fragment order ----------------
// Also zeroes bcur (consumed by binpass, launched after) and pooled (consumed by
// pool_kernel) -- replaces 2 hipMemsetAsync dispatches; same-stream ordering
// guarantees visibility.
__global__ void build_wfrag(const float* __restrict__ bw, const float* __restrict__ sw,
                            const float* __restrict__ sc, unsigned short* __restrict__ wfrag,
                            int* __restrict__ bcur, float* __restrict__ pooled){
  int idx = blockIdx.x*256 + threadIdx.x;
  if (idx < NBUK) bcur[idx] = 0;
  if (idx >= 256 && idx < 256 + NGR*DD) pooled[idx - 256] = 0.f;
  if (idx >= 3*128*1024) return;
  int k = idx & 1023;
  int o = (idx >> 10) & 127;
  int l = idx >> 17;
  int i = k >> 3, f = k & 7;
  int oi = (l*DD + o)*DD + i;
  float w = (f == 0) ? bw[oi] : sw[oi*7 + (f-1)] * sc[oi];
  int s = k >> 6;
  int sl = (k >> 4) & 3, half = (k >> 3) & 1, j = k & 7;
  int ntile = o >> 5, n = o & 31;
  int dst = l*131072 + s*8192 + (((ntile*4 + sl)*64) + half*32 + n)*8 + j;
  wfrag[dst] = (unsigned short)f2bf(w);
}

// ---------------- fused KAN feats + GEMM + pack + attention logits ----------------
// 32-row tile / 1563 blocks: LDS 25 KB. launch_bounds(256,4): VGPR cap 128 so
// the Bc/Bn double-buffer + acc stay in registers. 6 blocks/CU via LDS.
__global__ __launch_bounds__(256, 4) void kan_gemm(const float* __restrict__ xin,
                                                const unsigned short* __restrict__ wfrag,
                                                const float* __restrict__ attS,
                                                const float* __restrict__ attD,
                                                unsigned int* __restrict__ hpack,
                                                float* __restrict__ asrc,
                                                float* __restrict__ adst, int layer)
{
  __shared__ __align__(16) float xs[32*132];               // 16896 B (reused as hs)
  __shared__ __align__(16) unsigned short Afrag[2][2048];  // 8192 B
  const int t    = threadIdx.x;
  const int lane = t & 63;
  const int w    = t >> 6;          // wave -> output col tile w*32
  const int half = lane >> 5;
  const int mn   = lane & 31;
  const int row0 = blockIdx.x * 32;
  const int r_my = t & 31;          // row this thread packs
  const int j_my = t >> 5;          // col-in-step this thread packs (0..7)
  const unsigned short* wl = wfrag + layer*131072;

  // stage x rows [row0, row0+32) x 128 cols, float4-coalesced
#pragma unroll
  for (int q=0;q<4;++q){
    int p = q*256 + t;
    int r = p >> 5, c4 = p & 31;
    int grow = row0 + r;
    float4 v = make_float4(0.f,0.f,0.f,0.f);
    if (grow < NN) v = *(const float4*)(xin + (size_t)grow*DD + c4*4);
    *(float4*)(&xs[r*132 + c4*4]) = v;
  }
  __syncthreads();

  float16_t acc;
#pragma unroll
  for (int i=0;i<16;++i) acc[i]=0.f;

  int4 Bc[4], Bn[4];
#pragma unroll
  for (int sl=0;sl<4;++sl)
    Bc[sl] = *(const int4*)(wl + ((w*4+sl)*64 + lane)*8);

  // Afrag slot for (col j, row r) = ((j*32 + r)*8) ushorts
  const int fo = (j_my*32 + r_my)*8;
  {
    int4 P = kan_feats_pack(xs[r_my*132 + j_my]);
    *(int4*)(&Afrag[0][fo]) = P;
  }
  __syncthreads();

  for (int s=0; s<16; ++s){
    if (s < 15){
      const unsigned short* wsrc = wl + (s+1)*8192;
#pragma unroll
      for (int sl=0;sl<4;++sl)
        Bn[sl] = *(const int4*)(wsrc + ((w*4+sl)*64 + lane)*8);
      int4 P = kan_feats_pack(xs[r_my*132 + (s+1)*8 + j_my]);
      *(int4*)(&Afrag[(s+1)&1][fo]) = P;
    }
    const unsigned short* A = Afrag[s&1];
#pragma unroll
    for (int sl=0; sl<4; ++sl){
      int4 ai = *(const int4*)(A + ((sl*2 + half)*32 + mn)*8);
      bf16x8 b = __builtin_bit_cast(bf16x8, Bc[sl]);
      acc = __builtin_amdgcn_mfma_f32_32x32x16_bf16(__builtin_bit_cast(bf16x8, ai), b, acc, 0, 0, 0);
    }
#pragma unroll
    for (int sl=0;sl<4;++sl) Bc[sl] = Bn[sl];
    __syncthreads();
  }

  // epilogue: bf16-pack into LDS (reuse xs), then coalesced hpack write + att logits
  unsigned short* hs = (unsigned short*)xs;
#pragma unroll
  for (int reg=0; reg<16; ++reg){
    int row = (reg&3) + 8*(reg>>2) + 4*half;
    int col = w*32 + mn;
    hs[row*136 + col] = (unsigned short)f2bf(acc[reg]);
  }
  __syncthreads();
#pragma unroll
  for (int q=0;q<2;++q){
    int p = q*256 + t;
    int row = p >> 4, u4 = p & 15;
    uint4 v = *(const uint4*)((const unsigned int*)(hs + row*136) + u4*4);
    int grow = row0 + row;
    if (grow < NN) *(uint4*)(hpack + (size_t)grow*64 + u4*4) = v;
  }
  if (t < 128){
    int r = t >> 2, h = t & 3;
    const unsigned* hrow = (const unsigned*)(hs + r*136) + h*16;
    const float* ws = attS + (layer*4 + h)*32;
    const float* wd = attD + (layer*4 + h)*32;
    float ss = 0.f, sd = 0.f;
#pragma unroll
    for (int j=0;j<16;++j){
      unsigned u = hrow[j];
      float flo = __uint_as_float(u << 16);
      float fhi = __uint_as_float(u & 0xffff0000u);
      ss += flo*ws[2*j] + fhi*ws[2*j+1];
      sd += flo*wd[2*j] + fhi*wd[2*j+1];
    }
    int grow = row0 + r;
    if (grow < NN){ asrc[grow*4 + h] = ss; adst[grow*4 + h] = sd; }
  }
}

// ---------------- GAT aggregation v6 (measured optimum: interleaved load/FMA,
// ~20 waves/CU; issue-early variant regressed via occupancy): uint4 gathers ----
__global__ __launch_bounds__(256) void attn_kernel(
    const unsigned int* __restrict__ hpack, const float* __restrict__ asrc, const float* __restrict__ adst,
    const int* __restrict__ offs, const int* __restrict__ deg, const int* __restrict__ csr,
    const float* __restrict__ bias, float* __restrict__ hout, int layer)
{
  const int wave = threadIdx.x >> 6;
  const int lane = threadIdx.x & 63;
  const int n = blockIdx.x*4 + wave;
  if (n >= NN) return;
  const int st = offs[n];
  const int d  = deg[n];
  const int eL = lane >> 2, h = lane & 3;
  const float adh = adst[n*4 + h];

  // ---- phase 1: logits, running max ----
  int   srcv[4];
  float ev[4];
  float mL = -3.4e38f;
#pragma unroll
  for (int c=0;c<4;++c){
    srcv[c] = 0; ev[c] = -3.4e38f;
    if (c*16 < d){
      int e = c*16 + eL;
      if (e < d){
        int s2 = csr[st + e];
        srcv[c] = s2;
        float e0 = asrc[s2*4 + h] + adh;
        ev[c] = (e0 > 0.f) ? e0 : 0.2f*e0;
        mL = fmaxf(mL, ev[c]);
      }
    }
  }
  for (int c=64; c<d; c+=16){
    int e = c + eL;
    if (e < d){
      int s2 = csr[st + e];
      float e0 = asrc[s2*4 + h] + adh;
      float evv = (e0 > 0.f) ? e0 : 0.2f*e0;
      mL = fmaxf(mL, evv);
    }
  }
#pragma unroll
  for (int o=4;o<64;o<<=1) mL = fmaxf(mL, __shfl_xor(mL, o));

  // ---- phase 2: softmax denominator ----
  float av4[4];
  float sL = 0.f;
#pragma unroll
  for (int c=0;c<4;++c){ av4[c] = __expf(ev[c] - mL); sL += av4[c]; }
  for (int c=64; c<d; c+=16){
    int e = c + eL;
    if (e < d){
      int s2 = csr[st + e];
      float e0 = asrc[s2*4 + h] + adh;
      float evv = (e0 > 0.f) ? e0 : 0.2f*e0;
      sL += __expf(evv - mL);
    }
  }
#pragma unroll
  for (int o=4;o<64;o<<=1) sL += __shfl_xor(sL, o);
  const float inv = 1.f/(sL + 1e-16f);

  // ---- phase 3: weighted gather, uint4 layout ----
  const int cq   = lane >> 4;      // row-in-group 0..3
  const int cl   = lane & 15;      // col-quad 0..15
  const int hsel = cl >> 2;        // head owning my cols
  float acc8[8];
#pragma unroll
  for (int k=0;k<8;++k) acc8[k] = 0.f;

#pragma unroll
  for (int c=0;c<4;++c){
    if (c*16 < d){
      float ac = av4[c] * inv;     // 0 for invalid edges (exp(-inf))
#pragma unroll
      for (int g=0; g<4; ++g){
        if (c*16 + g*4 < d){
          int   sj = __shfl(srcv[c], (g*4 + cq)*4);
          float aj = __shfl(ac,      (g*4 + cq)*4 + hsel);
          uint4 u  = *(const uint4*)(hpack + (size_t)sj*64 + cl*4);
          acc8[0] = fmaf(aj, bflo(u.x), acc8[0]);
          acc8[1] = fmaf(aj, bfhi(u.x), acc8[1]);
          acc8[2] = fmaf(aj, bflo(u.y), acc8[2]);
          acc8[3] = fmaf(aj, bfhi(u.y), acc8[3]);
          acc8[4] = fmaf(aj, bflo(u.z), acc8[4]);
          acc8[5] = fmaf(aj, bfhi(u.z), acc8[5]);
          acc8[6] = fmaf(aj, bflo(u.w), acc8[6]);
          acc8[7] = fmaf(aj, bfhi(u.w), acc8[7]);
        }
      }
    }
  }
  // tail (d > 64): same uint4 pattern, logits recomputed per 16-edge chunk
  for (int c0=64; c0<d; c0+=16){
    int e = c0 + eL;
    int s2 = 0; float al = 0.f;
    if (e < d){
      s2 = csr[st + e];
      float e0 = asrc[s2*4 + h] + adh;
      float evv = (e0 > 0.f) ? e0 : 0.2f*e0;
      al = __expf(evv - mL) * inv;
    }
#pragma unroll
    for (int g=0; g<4; ++g){
      if (c0 + g*4 < d){
        int   sj = __shfl(s2, (g*4 + cq)*4);
        float aj = __shfl(al, (g*4 + cq)*4 + hsel);
        uint4 u  = *(const uint4*)(hpack + (size_t)sj*64 + cl*4);
        acc8[0] = fmaf(aj, bflo(u.x), acc8[0]);
        acc8[1] = fmaf(aj, bfhi(u.x), acc8[1]);
        acc8[2] = fmaf(aj, bflo(u.y), acc8[2]);
        acc8[3] = fmaf(aj, bfhi(u.y), acc8[3]);
        acc8[4] = fmaf(aj, bflo(u.z), acc8[4]);
        acc8[5] = fmaf(aj, bfhi(u.z), acc8[5]);
        acc8[6] = fmaf(aj, bflo(u.w), acc8[6]);
        acc8[7] = fmaf(aj, bfhi(u.w), acc8[7]);
      }
    }
  }

  // reduce the 4 row-groups (lanes differing in bits 4,5 hold same cols)
#pragma unroll
  for (int o=16;o<64;o<<=1){
#pragma unroll
    for (int k=0;k<8;++k) acc8[k] += __shfl_xor(acc8[k], o);
  }

  if (cq == 0){
    const float* bp = bias + layer*DD + cl*8;
    float4 b0 = *(const float4*)(bp);
    float4 b1 = *(const float4*)(bp + 4);
    float4 o0, o1;
    o0.x = siluf(acc8[0] + b0.x); o0.y = siluf(acc8[1] + b0.y);
    o0.z = siluf(acc8[2] + b0.z); o0.w = siluf(acc8[3] + b0.w);
    o1.x = siluf(acc8[4] + b1.x); o1.y = siluf(acc8[5] + b1.y);
    o1.z = siluf(acc8[6] + b1.z); o1.w = siluf(acc8[7] + b1.w);
    float* op = hout + (size_t)n*DD + cl*8;
    *(float4*)(op)     = o0;
    *(float4*)(op + 4) = o1;
  }
}

// ---------------- global_add_pool v2 (batch sorted): 256-row blocks,
// float4 loads, LDS-staged batch ids, register run-accumulate, boundary atomics
#define PROWS 256
__global__ __launch_bounds__(256) void pool_kernel(const float* __restrict__ h,
    const int* __restrict__ batch, float* __restrict__ pooled)
{
  __shared__ int gb[PROWS];
  const int t  = threadIdx.x;
  const int n0 = blockIdx.x * PROWS;
  {
    int n = n0 + t;
    gb[t] = (n < NN) ? batch[n] : -1;
  }
  __syncthreads();
  const int cq = t & 31;           // col quad: cols [cq*4, cq*4+4)
  const int rg = t >> 5;           // row group 0..7
  float4 sum = make_float4(0.f,0.f,0.f,0.f);
  int cur = -1;
#pragma unroll 4
  for (int k = 0; k < PROWS/8; ++k){
    int r = rg + k*8;
    int n = n0 + r;
    if (n >= NN) break;
    int g = gb[r];
    if (g != cur){
      if (cur >= 0){
        float* pp = pooled + cur*DD + cq*4;
        atomicAdd(pp+0, sum.x); atomicAdd(pp+1, sum.y);
        atomicAdd(pp+2, sum.z); atomicAdd(pp+3, sum.w);
      }
      cur = g; sum = make_float4(0.f,0.f,0.f,0.f);
    }
    float4 v = *(const float4*)(h + (size_t)n*DD + cq*4);
    sum.x += v.x; sum.y += v.y; sum.z += v.z; sum.w += v.w;
  }
  if (cur >= 0){
    float* pp = pooled + cur*DD + cq*4;
    atomicAdd(pp+0, sum.x); atomicAdd(pp+1, sum.y);
    atomicAdd(pp+2, sum.z); atomicAdd(pp+3, sum.w);
  }
}

// ---------------- KAN readout + log_softmax (1 block per graph) ----------------
__global__ __launch_bounds__(64) void readout_kernel(const float* __restrict__ pooled,
    const float* __restrict__ bw, const float* __restrict__ sw, const float* __restrict__ sc,
    float* __restrict__ out)
{
  int g = blockIdx.x, lane = threadIdx.x;
  float xa = pooled[g*DD + lane];
  float xb = pooled[g*DD + lane + 64];
  float fa[8], fb[8];
  kan_feats(xa, fa);
  kan_feats(xb, fb);
  float logits[NCL];
#pragma unroll
  for (int c=0;c<NCL;++c){
    int ia = c*DD + lane, ib = ia + 64;
    float sca = sc[ia], scb = sc[ib];
    float p = fa[0]*bw[ia] + fb[0]*bw[ib];
#pragma unroll
    for (int f=1;f<8;++f)
      p += fa[f]*sw[ia*7 + f-1]*sca + fb[f]*sw[ib*7 + f-1]*scb;
#pragma unroll
    for (int o=1;o<64;o<<=1) p += __shfl_xor(p, o);
    logits[c] = p;
  }
  float mx = logits[0];
#pragma unroll
  for (int c=1;c<NCL;++c) mx = fmaxf(mx, logits[c]);
  float lse = 0.f;
#pragma unroll
  for (int c=0;c<NCL;++c) lse += __expf(logits[c]-mx);
  lse = mx + logf(lse);
  if (lane < NCL){
    float v = 0.f;
#pragma unroll
    for (int c=0;c<NCL;++c) if (lane == c) v = logits[c] - lse;
    out[g*NCL + lane] = v;
  }
}

// ---------------- host ----------------
extern "C" void kernel_launch(void* const* d_in, const int* in_sizes, int n_in,
                              void* d_out, int out_size, void* d_ws, size_t ws_size,
                              hipStream_t stream)
{
  const float* x        = (const float*)d_in[0];
  const int*   ei       = (const int*)  d_in[1];
  const int*   batch    = (const int*)  d_in[2];
  const float* base_w   = (const float*)d_in[3];
  const float* spline_w = (const float*)d_in[4];
  const float* scaler   = (const float*)d_in[5];
  const float* att_src  = (const float*)d_in[6];
  const float* att_dst  = (const float*)d_in[7];
  const float* bias     = (const float*)d_in[8];
  const float* ro_bw    = (const float*)d_in[9];
  const float* ro_sw    = (const float*)d_in[10];
  const float* ro_sc    = (const float*)d_in[11];
  float* out = (float*)d_out;

  char* p = (char*)d_ws;
  auto alloc = [&](size_t bytes)->char* {
    char* r = p;
    p += (bytes + 255) & ~(size_t)255;
    return r;
  };
  unsigned int* hpack = (unsigned int*)alloc((size_t)50048*64*4);
  float* hbuf   = (float*)alloc((size_t)NN*DD*4);
  unsigned short* wfrag = (unsigned short*)alloc((size_t)3*131072*2);
  float* asrc   = (float*)alloc((size_t)NN*4*4);
  float* adst   = (float*)alloc((size_t)NN*4*4);
  float* pooled = (float*)alloc((size_t)NGR*DD*4);
  int*   deg    = (int*)alloc((size_t)NN*4);
  int*   offs   = (int*)alloc((size_t)NN*4);
  int*   csr    = (int*)alloc((size_t)ETOT*4);
  unsigned* tmp = (unsigned*)alloc((size_t)NBUK*TCAP*4);
  int*   bcur   = (int*)alloc((size_t)NBUK*4);

  // build_wfrag also zeroes bcur + pooled (replaces 2 memset dispatches)
  build_wfrag   <<<(3*128*1024)/256, 256, 0, stream>>>(base_w, spline_w, scaler,
                                                       wfrag, bcur, pooled);
  binpass_kernel<<<P1GRID, 256, 0, stream>>>(ei, bcur, tmp);
  scatter_kernel<<<NBUK,  256, 0, stream>>>(tmp, bcur, offs, deg, csr);

  const float* cur = x;
  for (int l=0; l<3; ++l){
    kan_gemm   <<<(NN+31)/32, 256, 0, stream>>>(cur, wfrag, att_src, att_dst,
                                                hpack, asrc, adst, l);
    attn_kernel<<<(NN+3)/4,   256, 0, stream>>>(hpack, asrc, adst, offs, deg, csr,
                                                bias, hbuf, l);
    cur = hbuf;
  }
  pool_kernel   <<<(NN+255)/PROWS, 256, 0, stream>>>(hbuf, batch, pooled);
  readout_kernel<<<NGR, 64, 0, stream>>>(pooled, ro_bw, ro_sw, ro_sc, out);
}